// Round 6
// baseline (317.105 us; speedup 1.0000x reference)
//
#include <hip/hip_runtime.h>
#include <hip/hip_fp16.h>

#define H_IMG 256
#define W_IMG 512
#define NPIX  (H_IMG*W_IMG)   // 131072
#define BATCH 4
#define HID   64

#define TX 32
#define TY 8
#define HX (TX+2)   // 34
#define HY (TY+2)   // 10
#define HN (HX*HY)  // 340
#define SSTR 76     // halfs per node (152 B; validated conflict-free in R5)
#define LTH 256

typedef _Float16 half8 __attribute__((ext_vector_type(8)));
typedef float v4f __attribute__((ext_vector_type(4)));

__device__ __forceinline__ float rs1(int v, int n) {
  return rsqrtf((float)(3 - (v==0) - (v==(n-1))));
}

__device__ __forceinline__ unsigned pack2(float a, float b) {
  __half2 h = __floats2half2_rn(a, b);
  return *reinterpret_cast<unsigned*>(&h);
}

// WgT[l][f][k] = fp16(Wg[l][k][f])
__global__ void k_wg(const float* __restrict__ Wg, __half* __restrict__ WgT) {
  int idx = blockIdx.x * 256 + threadIdx.x;          // 3*64*64 = 12288
  int l = idx >> 12, rem = idx & 4095;
  int f = rem >> 6, k = rem & 63;
  WgT[idx] = __float2half(Wg[(l << 12) + (k << 6) + f]);
}

// h0[b,n,f] = x[b,:,n] @ W_in + b_in   (stored fp16)
__global__ void k_in(const float* __restrict__ x, const float* __restrict__ W_in,
                     const float* __restrict__ b_in, __half* __restrict__ h) {
  int idx = blockIdx.x * 256 + threadIdx.x;
  int f4 = idx & 15;
  int bn = idx >> 4;
  int b  = bn >> 17;
  int n  = bn & (NPIX-1);
  const float* xb = x + (size_t)b*3*NPIX + n;
  float x0 = xb[0], x1 = xb[NPIX], x2 = xb[2*NPIX];
  const float4 w0 = *(const float4*)&W_in[      f4*4];
  const float4 w1 = *(const float4*)&W_in[ 64 + f4*4];
  const float4 w2 = *(const float4*)&W_in[128 + f4*4];
  const float4 bi = *(const float4*)&b_in[f4*4];
  float r0 = bi.x + x0*w0.x + x1*w1.x + x2*w2.x;
  float r1 = bi.y + x0*w0.y + x1*w1.y + x2*w2.y;
  float r2 = bi.z + x0*w0.z + x1*w1.z + x2*w2.z;
  float r3 = bi.w + x0*w0.w + x1*w1.w + x2*w2.w;
  uint2 pk; pk.x = pack2(r0, r1); pk.y = pack2(r2, r3);
  *reinterpret_cast<uint2*>(h + (size_t)bn*64 + (size_t)f4*4) = pk;
}

// One GCN layer: h' = relu( S(h) @ Wg + bg ); S separable: Sy (x) Sx.
// Stencil fp32-accumulated from fp16 LDS halo; GEMM via MFMA f16 (fp32 acc).
__global__ __launch_bounds__(LTH, 3) void k_layer(
    const __half* __restrict__ hin, const __half* __restrict__ wgt,
    const float* __restrict__ bg, __half* __restrict__ hout) {
  __shared__ __half hs[HN * SSTR];   // 51,680 B -> 3 blocks/CU
  const int tid = threadIdx.x;

  // natural mapping (R2-validated L2 locality; R5's XCD swizzle regressed it)
  const int tx0 = blockIdx.x * TX;
  const int ty0 = blockIdx.y * TY;
  const int b   = blockIdx.z;
  const __half* hb = hin + (size_t)b * NPIX * HID;

  const int l64 = tid & 63, lm = l64 & 15, lh = l64 >> 4, w = tid >> 6;

  // A fragments (WgT, fp16) + bias C-input, straight from global (L2-hot)
  half8 af0[4], af1[4];
  v4f cb[4];
#pragma unroll
  for (int ft = 0; ft < 4; ++ft) {
    const __half* wp = wgt + (ft*16 + lm)*64 + lh*8;
    af0[ft] = *(const half8*)wp;
    af1[ft] = *(const half8*)(wp + 32);
    cb[ft] = *(const v4f*)(bg + ft*16 + (lh << 2));
  }

  // stage halo tile (raw fp16, OOB -> 0)
  for (int it = tid; it < HN*8; it += LTH) {
    int c8 = it & 7, nl = it >> 3;
    int row = nl / HX, col = nl - row*HX;
    int sy = ty0 - 1 + row, sx = tx0 - 1 + col;
    uint4 v = make_uint4(0u,0u,0u,0u);
    if ((unsigned)sy < H_IMG && (unsigned)sx < W_IMG)
      v = *(const uint4*)(hb + ((size_t)((sy << 9) + sx)) * 64 + (c8 << 3));
    *(uint4*)&hs[nl*SSTR + (c8 << 3)] = v;
  }
  __syncthreads();

  // ---- separable stencil, column-rolling over 10 halo rows ----
  const int cx = tid & 31;        // output column within tile
  const int c8 = tid >> 5;        // channel octet
  const int gxc = tx0 + cx;
  const float rxm = rs1(gxc-1, W_IMG), rxc = rs1(gxc, W_IMG), rxp = rs1(gxc+1, W_IMG);
  const float cxm = rxc*rxm, cxc = rxc*rxc, cxp = rxc*rxp;
  float ryv[HY];
#pragma unroll
  for (int y = 0; y < HY; ++y) ryv[y] = rs1(ty0 - 1 + y, H_IMG);

  v4f t0a = (v4f)0, t0b = (v4f)0, t1a = (v4f)0, t1b = (v4f)0;
  uint4 sreg[TY];
#pragma unroll
  for (int y = 0; y < HY; ++y) {
    const __half* hp = &hs[(y*HX + cx)*SSTR + (c8 << 3)];
    half8 vL = *(const half8*)hp;
    half8 vC = *(const half8*)(hp + SSTR);
    half8 vR = *(const half8*)(hp + 2*SSTR);
    v4f na, nb;
#pragma unroll
    for (int k = 0; k < 4; ++k) {
      na[k] = fmaf(cxp,(float)vR[k],   fmaf(cxc,(float)vC[k],   cxm*(float)vL[k]));
      nb[k] = fmaf(cxp,(float)vR[k+4], fmaf(cxc,(float)vC[k+4], cxm*(float)vL[k+4]));
    }
    if (y >= 2) {
      const int yo = y - 2;
      const float am = ryv[yo+1]*ryv[yo], ac = ryv[yo+1]*ryv[yo+1], ap = ryv[yo+1]*ryv[yo+2];
      v4f sa, sb;
#pragma unroll
      for (int k = 0; k < 4; ++k) {
        sa[k] = fmaf(ap, na[k], fmaf(ac, t1a[k], am*t0a[k]));
        sb[k] = fmaf(ap, nb[k], fmaf(ac, t1b[k], am*t0b[k]));
      }
      sreg[yo] = make_uint4(pack2(sa[0],sa[1]), pack2(sa[2],sa[3]),
                            pack2(sb[0],sb[1]), pack2(sb[2],sb[3]));
    }
    t0a = t1a; t0b = t1b; t1a = na; t1b = nb;
  }
  __syncthreads();                 // all halo reads done; safe to overwrite

  // spill s (fp16) into LDS: node-major [256][SSTR], MFMA-fragment layout
#pragma unroll
  for (int yo = 0; yo < TY; ++yo)
    *(uint4*)&hs[((yo << 5) + cx)*SSTR + (c8 << 3)] = sreg[yo];
  __syncthreads();

  // GEMM: D = WgT (64f x 64k) x s^T (64k x nodes); D[f][node]
  __half* ho = hout + (size_t)b * NPIX * HID;
#pragma unroll
  for (int i = 0; i < 4; ++i) {
    int g  = (w << 2) + i;          // node group: 16 nodes
    int nn = (g << 4) + lm;         // local node for this lane
    const __half* sp = &hs[nn*SSTR + (lh << 3)];
    half8 b0 = *(const half8*)sp;
    half8 b1 = *(const half8*)(sp + 32);
    v4f d[4];
#pragma unroll
    for (int ft = 0; ft < 4; ++ft) {
      v4f t = __builtin_amdgcn_mfma_f32_16x16x32_f16(af0[ft], b0, cb[ft], 0, 0, 0);
      d[ft]  = __builtin_amdgcn_mfma_f32_16x16x32_f16(af1[ft], b1, t,     0, 0, 0);
    }
    // lane holds features ft*16 + lh*4 + r of node nn
    __half* hp = ho + (size_t)(((ty0 + (nn >> 5)) << 9) + tx0 + (nn & 31)) * HID + (lh << 2);
#pragma unroll
    for (int ft = 0; ft < 4; ++ft) {
      uint2 u;
      u.x = pack2(fmaxf(d[ft][0], 0.f), fmaxf(d[ft][1], 0.f));
      u.y = pack2(fmaxf(d[ft][2], 0.f), fmaxf(d[ft][3], 0.f));
      *(uint2*)(hp + ft*16) = u;
    }
  }
}

// out[b,c,n] = h[b,n,:] @ W_out + b_out
__global__ void k_out(const __half* __restrict__ h, const float* __restrict__ W_out,
                      const float* __restrict__ b_out, float* __restrict__ out) {
  int idx = blockIdx.x * 256 + threadIdx.x;
  int c8 = idx & 7;
  int bn = idx >> 3;
  uint4 raw = *reinterpret_cast<const uint4*>(h + (size_t)bn*64 + (size_t)c8*8);
  const __half2* hp = reinterpret_cast<const __half2*>(&raw);
  float p0 = 0.f, p1 = 0.f, p2 = 0.f;
  int fbase = c8*8;
#pragma unroll
  for (int j = 0; j < 4; ++j) {
    float2 f = __half22float2(hp[j]);
    const float* wv = &W_out[(fbase + j*2)*3];
    p0 += f.x*wv[0] + f.y*wv[3];
    p1 += f.x*wv[1] + f.y*wv[4];
    p2 += f.x*wv[2] + f.y*wv[5];
  }
#pragma unroll
  for (int m = 1; m < 8; m <<= 1) {
    p0 += __shfl_xor(p0, m);
    p1 += __shfl_xor(p1, m);
    p2 += __shfl_xor(p2, m);
  }
  if (c8 == 0) {
    int b = bn >> 17, n = bn & (NPIX-1);
    out[((size_t)b*3 + 0)*NPIX + n] = p0 + b_out[0];
    out[((size_t)b*3 + 1)*NPIX + n] = p1 + b_out[1];
    out[((size_t)b*3 + 2)*NPIX + n] = p2 + b_out[2];
  }
}

extern "C" void kernel_launch(void* const* d_in, const int* in_sizes, int n_in,
                              void* d_out, int out_size, void* d_ws, size_t ws_size,
                              hipStream_t stream) {
  const float* x     = (const float*)d_in[0];
  // d_in[1] = src, d_in[2] = dst — unused: grid topology is analytic
  const float* W_in  = (const float*)d_in[3];
  const float* b_in  = (const float*)d_in[4];
  const float* Wg    = (const float*)d_in[5];
  const float* bg    = (const float*)d_in[6];
  const float* W_out = (const float*)d_in[7];
  const float* b_out = (const float*)d_in[8];
  float* out = (float*)d_out;

  // WgT fp16 scratch lives at the head of d_out; k_out overwrites it at the end.
  __half* WgT = (__half*)d_out;
  __half* hA = (__half*)d_ws;
  __half* hB = hA + (size_t)BATCH*NPIX*HID;

  k_wg<<<dim3(48), 256, 0, stream>>>(Wg, WgT);
  k_in<<<dim3(BATCH*NPIX*16/256), 256, 0, stream>>>(x, W_in, b_in, hA);

  dim3 lg(W_IMG/TX, H_IMG/TY, BATCH);   // 16 x 32 x 4
  k_layer<<<lg, LTH, 0, stream>>>(hA, WgT,        bg,       hB);
  k_layer<<<lg, LTH, 0, stream>>>(hB, WgT + 4096, bg + 64,  hA);
  k_layer<<<lg, LTH, 0, stream>>>(hA, WgT + 8192, bg + 128, hB);

  k_out<<<dim3(BATCH*NPIX*8/256), 256, 0, stream>>>(hB, W_out, b_out, out);
}

// Round 8
// 158.531 us; speedup vs baseline: 2.0003x; 2.0003x over previous
//
#include <hip/hip_runtime.h>
#include <hip/hip_fp16.h>

#define H_IMG 256
#define W_IMG 512
#define NPIX  (H_IMG*W_IMG)   // 131072
#define BATCH 4
#define HID   64

#define TX 32
#define TY 8
#define HX (TX+2)   // 34
#define HY (TY+2)   // 10
#define HN (HX*HY)  // 340
#define SSTR 72     // EXACT R2 layout (proven 52 us/layer, replay-deterministic)
#define LTH 256

typedef _Float16 half8 __attribute__((ext_vector_type(8)));
typedef float v4f __attribute__((ext_vector_type(4)));

__device__ __forceinline__ float dinvf(int y, int x) {
  int cy = 3 - (y==0) - (y==(H_IMG-1));
  int cx = 3 - (x==0) - (x==(W_IMG-1));
  return rsqrtf((float)(cy*cx));
}

__device__ __forceinline__ unsigned pack2(float a, float b) {
  __half2 h = __floats2half2_rn(a, b);
  return *reinterpret_cast<unsigned*>(&h);
}

// WgT[l][f][k] = fp16(Wg[l][k][f])   (EXACT R2)
__global__ void k_wg(const float* __restrict__ Wg, __half* __restrict__ WgT) {
  int idx = blockIdx.x * 256 + threadIdx.x;          // 3*64*64 = 12288
  int l = idx >> 12, rem = idx & 4095;
  int f = rem >> 6, k = rem & 63;
  WgT[idx] = __float2half(Wg[(l << 12) + (k << 6) + f]);
}

// One GCN layer (R2-proven internals).
// MODE 0: stage h0 = x@W_in+b_in on the fly (fuses k_in); MODE 1: stage from hin.
template<int MODE>
__global__ __launch_bounds__(LTH, 3) void k_layer(
    const float* __restrict__ x,
    const float* __restrict__ W_in, const float* __restrict__ b_in,
    const __half* __restrict__ hin, const __half* __restrict__ wgt,
    const float* __restrict__ bg, __half* __restrict__ hout) {
  __shared__ __half hs[HN * SSTR];   // 48,960 B -> 3 blocks/CU
  const int tid = threadIdx.x;
  const int tx0 = blockIdx.x * TX;
  const int ty0 = blockIdx.y * TY;
  const int b   = blockIdx.z;

  const int l64 = tid & 63, lm = l64 & 15, lh = l64 >> 4, w = tid >> 6;

  // A fragments (WgT, fp16) + bias C-input (EXACT R2)
  half8 af0[4], af1[4];
  v4f cb[4];
#pragma unroll
  for (int ft = 0; ft < 4; ++ft) {
    const __half* wp = wgt + (ft*16 + lm)*64 + lh*8;
    af0[ft] = *(const half8*)wp;
    af1[ft] = *(const half8*)(wp + 32);
    cb[ft] = *(const v4f*)(bg + ft*16 + (lh << 2));
  }

  // ---- staging ----
  if (MODE == 0) {
    // h0 halo built on the fly from x (W_in/b_in thread-uniform -> s_loads)
    const float* xb = x + (size_t)b*3*NPIX;
    for (int n = tid; n < HN; n += LTH) {
      int row = n / HX, col = n - row*HX;
      int gy = ty0 - 1 + row, gx = tx0 - 1 + col;
      __half* hp = &hs[n*SSTR];
      if ((unsigned)gy < H_IMG && (unsigned)gx < W_IMG) {
        int gi = (gy << 9) + gx;
        float x0 = xb[gi], x1 = xb[NPIX+gi], x2 = xb[2*NPIX+gi];
#pragma unroll
        for (int c8 = 0; c8 < 8; ++c8) {
          float rr[8];
#pragma unroll
          for (int k = 0; k < 8; ++k) {
            int f = (c8 << 3) + k;
            rr[k] = fmaf(x0, W_in[f], fmaf(x1, W_in[64+f], fmaf(x2, W_in[128+f], b_in[f])));
          }
          *(uint2*)(hp + (c8<<3))     = make_uint2(pack2(rr[0],rr[1]), pack2(rr[2],rr[3]));
          *(uint2*)(hp + (c8<<3) + 4) = make_uint2(pack2(rr[4],rr[5]), pack2(rr[6],rr[7]));
        }
      } else {
        uint2 z = make_uint2(0u, 0u);
#pragma unroll
        for (int c8 = 0; c8 < 8; ++c8) {
          *(uint2*)(hp + (c8<<3)) = z; *(uint2*)(hp + (c8<<3) + 4) = z;
        }
      }
    }
  } else {
    // stage halo tile from hin (raw fp16, OOB -> 0)  (EXACT R2)
    const __half* hb = hin + (size_t)b * NPIX * HID;
    for (int it = tid; it < HN*8; it += LTH) {
      int c8 = it & 7, nl = it >> 3;
      int row = nl / HX, col = nl - row*HX;
      int sy = ty0 - 1 + row, sx = tx0 - 1 + col;
      uint4 v = make_uint4(0u,0u,0u,0u);
      if ((unsigned)sy < H_IMG && (unsigned)sx < W_IMG)
        v = *(const uint4*)(hb + ((size_t)((sy << 9) + sx)) * 64 + (c8 << 3));
      *(uint4*)&hs[nl*SSTR + (c8 << 3)] = v;
    }
  }
  __syncthreads();

  // ---- 9-point stencil, fp32 acc (EXACT R2) ----
  const int lx = tid & 31, ly = tid >> 5;
  const int gy = ty0 + ly, gx = tx0 + lx;
  const float dc = dinvf(gy, gx);
  float sc[9];
  int   nb[9];
#pragma unroll
  for (int r = 0; r < 3; ++r)
#pragma unroll
    for (int c = 0; c < 3; ++c) {
      sc[r*3+c] = dc * dinvf(gy-1+r, gx-1+c);
      nb[r*3+c] = ((ly+r)*HX + lx + c) * SSTR;
    }
  half8 sreg[8];
#pragma unroll
  for (int ch = 0; ch < 8; ++ch) {
    float acc[8] = {0.f,0.f,0.f,0.f,0.f,0.f,0.f,0.f};
#pragma unroll
    for (int j = 0; j < 9; ++j) {
      half8 v = *(const half8*)&hs[nb[j] + (ch << 3)];
      float s = sc[j];
#pragma unroll
      for (int k = 0; k < 8; ++k) acc[k] = fmaf(s, (float)v[k], acc[k]);
    }
    half8 o;
#pragma unroll
    for (int k = 0; k < 8; ++k) o[k] = (_Float16)acc[k];
    sreg[ch] = o;
  }
  __syncthreads();

  // spill s (fp16) into LDS, node-major (EXACT R2)
#pragma unroll
  for (int ch = 0; ch < 8; ++ch)
    *(half8*)&hs[tid*SSTR + (ch << 3)] = sreg[ch];
  __syncthreads();

  // ---- GEMM: D = WgT (64f x 64k) x s^T; D[f][node] (EXACT R2) ----
  __half* ho = hout + (size_t)b * NPIX * HID;
#pragma unroll
  for (int i = 0; i < 4; ++i) {
    int g  = (w << 2) + i;          // node group: 16 nodes
    int nn = (g << 4) + lm;         // local node for this lane
    const __half* sp = &hs[nn*SSTR + (lh << 3)];
    half8 b0 = *(const half8*)sp;
    half8 b1 = *(const half8*)(sp + 32);
    v4f d[4];
#pragma unroll
    for (int ft = 0; ft < 4; ++ft) {
      v4f t = __builtin_amdgcn_mfma_f32_16x16x32_f16(af0[ft], b0, cb[ft], 0, 0, 0);
      d[ft]  = __builtin_amdgcn_mfma_f32_16x16x32_f16(af1[ft], b1, t,     0, 0, 0);
    }
    __half* hp = ho + (size_t)(((ty0 + (nn >> 5)) << 9) + tx0 + (nn & 31)) * HID + (lh << 2);
#pragma unroll
    for (int ft = 0; ft < 4; ++ft) {
      uint2 u;
      u.x = pack2(fmaxf(d[ft][0], 0.f), fmaxf(d[ft][1], 0.f));
      u.y = pack2(fmaxf(d[ft][2], 0.f), fmaxf(d[ft][3], 0.f));
      *(uint2*)(hp + ft*16) = u;
    }
  }
}

// out[b,c,n] = h[b,n,:] @ W_out + b_out   (EXACT R2)
__global__ void k_out(const __half* __restrict__ h, const float* __restrict__ W_out,
                      const float* __restrict__ b_out, float* __restrict__ out) {
  int idx = blockIdx.x * 256 + threadIdx.x;
  int c8 = idx & 7;
  int bn = idx >> 3;
  uint4 raw = *reinterpret_cast<const uint4*>(h + (size_t)bn*64 + (size_t)c8*8);
  const __half2* hp = reinterpret_cast<const __half2*>(&raw);
  float p0 = 0.f, p1 = 0.f, p2 = 0.f;
  int fbase = c8*8;
#pragma unroll
  for (int j = 0; j < 4; ++j) {
    float2 f = __half22float2(hp[j]);
    const float* wv = &W_out[(fbase + j*2)*3];
    p0 += f.x*wv[0] + f.y*wv[3];
    p1 += f.x*wv[1] + f.y*wv[4];
    p2 += f.x*wv[2] + f.y*wv[5];
  }
#pragma unroll
  for (int m = 1; m < 8; m <<= 1) {
    p0 += __shfl_xor(p0, m);
    p1 += __shfl_xor(p1, m);
    p2 += __shfl_xor(p2, m);
  }
  if (c8 == 0) {
    int b = bn >> 17, n = bn & (NPIX-1);
    out[((size_t)b*3 + 0)*NPIX + n] = p0 + b_out[0];
    out[((size_t)b*3 + 1)*NPIX + n] = p1 + b_out[1];
    out[((size_t)b*3 + 2)*NPIX + n] = p2 + b_out[2];
  }
}

extern "C" void kernel_launch(void* const* d_in, const int* in_sizes, int n_in,
                              void* d_out, int out_size, void* d_ws, size_t ws_size,
                              hipStream_t stream) {
  const float* x     = (const float*)d_in[0];
  // d_in[1] = src, d_in[2] = dst — unused: grid topology is analytic
  const float* W_in  = (const float*)d_in[3];
  const float* b_in  = (const float*)d_in[4];
  const float* Wg    = (const float*)d_in[5];
  const float* bg    = (const float*)d_in[6];
  const float* W_out = (const float*)d_in[7];
  const float* b_out = (const float*)d_in[8];
  float* out = (float*)d_out;

  // WgT fp16 scratch at head of d_out (R2-proven: k_out fully overwrites later)
  __half* WgT = (__half*)d_out;
  __half* hA = (__half*)d_ws;
  __half* hB = hA + (size_t)BATCH*NPIX*HID;

  k_wg<<<dim3(48), 256, 0, stream>>>(Wg, WgT);

  dim3 lg(W_IMG/TX, H_IMG/TY, BATCH);   // 16 x 32 x 4
  k_layer<0><<<lg, LTH, 0, stream>>>(x, W_in, b_in, nullptr, WgT,        bg,       hA);
  k_layer<1><<<lg, LTH, 0, stream>>>(nullptr, nullptr, nullptr, hA, WgT + 4096, bg + 64,  hB);
  k_layer<1><<<lg, LTH, 0, stream>>>(nullptr, nullptr, nullptr, hB, WgT + 8192, bg + 128, hA);

  k_out<<<dim3(BATCH*NPIX*8/256), 256, 0, stream>>>(hA, W_out, b_out, out);
}

// Round 10
// 156.965 us; speedup vs baseline: 2.0202x; 1.0100x over previous
//
#include <hip/hip_runtime.h>
#include <hip/hip_fp16.h>

#define H_IMG 256
#define W_IMG 512
#define NPIX  (H_IMG*W_IMG)   // 131072
#define BATCH 4
#define HID   64

#define TX 16
#define TY 8
#define HX (TX+2)   // 18
#define HY (TY+2)   // 10
#define HN (HX*HY)  // 180
#define SSTR 72     // R2/R8-proven layout (144 B/node)
#define LTH 128

typedef _Float16 half8 __attribute__((ext_vector_type(8)));
typedef float v4f __attribute__((ext_vector_type(4)));

__device__ __forceinline__ float dinvf(int y, int x) {
  int cy = 3 - (y==0) - (y==(H_IMG-1));
  int cx = 3 - (x==0) - (x==(W_IMG-1));
  return rsqrtf((float)(cy*cx));
}

__device__ __forceinline__ unsigned pack2(float a, float b) {
  __half2 h = __floats2half2_rn(a, b);
  return *reinterpret_cast<unsigned*>(&h);
}

// WgT[l][f][k] = fp16(Wg[l][k][f])   (R2/R8-proven)
__global__ void k_wg(const float* __restrict__ Wg, __half* __restrict__ WgT) {
  int idx = blockIdx.x * 256 + threadIdx.x;          // 3*64*64 = 12288
  int l = idx >> 12, rem = idx & 4095;
  int f = rem >> 6, k = rem & 63;
  WgT[idx] = __float2half(Wg[(l << 12) + (k << 6) + f]);
}

// One GCN layer (R8-proven internals, 16x8 tile / 128 threads / 6 blocks/CU).
// MODE 0: stage h0 = x@W_in+b_in on the fly (fuses k_in); MODE 1: stage from hin.
template<int MODE>
__global__ __launch_bounds__(LTH, 3) void k_layer(
    const float* __restrict__ x,
    const float* __restrict__ W_in, const float* __restrict__ b_in,
    const __half* __restrict__ hin, const __half* __restrict__ wgt,
    const float* __restrict__ bg, __half* __restrict__ hout) {
  __shared__ __half hs[HN * SSTR];   // 25,920 B -> 6 blocks/CU
  const int tid = threadIdx.x;
  const int tx0 = blockIdx.x * TX;
  const int ty0 = blockIdx.y * TY;
  const int b   = blockIdx.z;

  const int l64 = tid & 63, lm = l64 & 15, lh = l64 >> 4, w = tid >> 6;

  // A fragments (WgT, fp16) + bias C-input (R8-proven)
  half8 af0[4], af1[4];
  v4f cb[4];
#pragma unroll
  for (int ft = 0; ft < 4; ++ft) {
    const __half* wp = wgt + (ft*16 + lm)*64 + lh*8;
    af0[ft] = *(const half8*)wp;
    af1[ft] = *(const half8*)(wp + 32);
    cb[ft] = *(const v4f*)(bg + ft*16 + (lh << 2));
  }

  // ---- staging ----
  if (MODE == 0) {
    // h0 halo built on the fly from x (W_in/b_in thread-uniform -> s_loads)
    const float* xb = x + (size_t)b*3*NPIX;
    for (int n = tid; n < HN; n += LTH) {
      int row = n / HX, col = n - row*HX;
      int gy = ty0 - 1 + row, gx = tx0 - 1 + col;
      __half* hp = &hs[n*SSTR];
      if ((unsigned)gy < H_IMG && (unsigned)gx < W_IMG) {
        int gi = (gy << 9) + gx;
        float x0 = xb[gi], x1 = xb[NPIX+gi], x2 = xb[2*NPIX+gi];
#pragma unroll
        for (int c8 = 0; c8 < 8; ++c8) {
          float rr[8];
#pragma unroll
          for (int k = 0; k < 8; ++k) {
            int f = (c8 << 3) + k;
            rr[k] = fmaf(x0, W_in[f], fmaf(x1, W_in[64+f], fmaf(x2, W_in[128+f], b_in[f])));
          }
          *(uint2*)(hp + (c8<<3))     = make_uint2(pack2(rr[0],rr[1]), pack2(rr[2],rr[3]));
          *(uint2*)(hp + (c8<<3) + 4) = make_uint2(pack2(rr[4],rr[5]), pack2(rr[6],rr[7]));
        }
      } else {
        uint2 z = make_uint2(0u, 0u);
#pragma unroll
        for (int c8 = 0; c8 < 8; ++c8) {
          *(uint2*)(hp + (c8<<3)) = z; *(uint2*)(hp + (c8<<3) + 4) = z;
        }
      }
    }
  } else {
    // stage halo tile from hin (raw fp16, OOB -> 0)  (R8-proven)
    const __half* hb = hin + (size_t)b * NPIX * HID;
    for (int it = tid; it < HN*8; it += LTH) {
      int c8 = it & 7, nl = it >> 3;
      int row = nl / HX, col = nl - row*HX;
      int sy = ty0 - 1 + row, sx = tx0 - 1 + col;
      uint4 v = make_uint4(0u,0u,0u,0u);
      if ((unsigned)sy < H_IMG && (unsigned)sx < W_IMG)
        v = *(const uint4*)(hb + ((size_t)((sy << 9) + sx)) * 64 + (c8 << 3));
      *(uint4*)&hs[nl*SSTR + (c8 << 3)] = v;
    }
  }
  __syncthreads();

  // ---- 9-point stencil, fp32 acc (R8-proven; 1 thread = 1 node) ----
  const int lx = tid & 15, ly = tid >> 4;
  const int gy = ty0 + ly, gx = tx0 + lx;
  const float dc = dinvf(gy, gx);
  float sc[9];
  int   nb[9];
#pragma unroll
  for (int r = 0; r < 3; ++r)
#pragma unroll
    for (int c = 0; c < 3; ++c) {
      sc[r*3+c] = dc * dinvf(gy-1+r, gx-1+c);
      nb[r*3+c] = ((ly+r)*HX + lx + c) * SSTR;
    }
  half8 sreg[8];
#pragma unroll
  for (int ch = 0; ch < 8; ++ch) {
    float acc[8] = {0.f,0.f,0.f,0.f,0.f,0.f,0.f,0.f};
#pragma unroll
    for (int j = 0; j < 9; ++j) {
      half8 v = *(const half8*)&hs[nb[j] + (ch << 3)];
      float s = sc[j];
#pragma unroll
      for (int k = 0; k < 8; ++k) acc[k] = fmaf(s, (float)v[k], acc[k]);
    }
    half8 o;
#pragma unroll
    for (int k = 0; k < 8; ++k) o[k] = (_Float16)acc[k];
    sreg[ch] = o;
  }
  __syncthreads();

  // spill s (fp16) into LDS, node-major (R8-proven)
#pragma unroll
  for (int ch = 0; ch < 8; ++ch)
    *(half8*)&hs[tid*SSTR + (ch << 3)] = sreg[ch];
  __syncthreads();

  // ---- GEMM: D = WgT (64f x 64k) x s^T; D[f][node] (R8-proven) ----
  __half* ho = hout + (size_t)b * NPIX * HID;
#pragma unroll
  for (int i = 0; i < 4; ++i) {
    int g  = (w << 2) + i;          // node group: 16 nodes (8 groups = 128 nodes)
    int nn = (g << 4) + lm;         // local node for this lane
    const __half* sp = &hs[nn*SSTR + (lh << 3)];
    half8 b0 = *(const half8*)sp;
    half8 b1 = *(const half8*)(sp + 32);
    v4f d[4];
#pragma unroll
    for (int ft = 0; ft < 4; ++ft) {
      v4f t = __builtin_amdgcn_mfma_f32_16x16x32_f16(af0[ft], b0, cb[ft], 0, 0, 0);
      d[ft]  = __builtin_amdgcn_mfma_f32_16x16x32_f16(af1[ft], b1, t,     0, 0, 0);
    }
    // node nn: row = nn>>4, col = nn&15
    __half* hp = ho + (size_t)(((ty0 + (nn >> 4)) << 9) + tx0 + (nn & 15)) * HID + (lh << 2);
#pragma unroll
    for (int ft = 0; ft < 4; ++ft) {
      uint2 u;
      u.x = pack2(fmaxf(d[ft][0], 0.f), fmaxf(d[ft][1], 0.f));
      u.y = pack2(fmaxf(d[ft][2], 0.f), fmaxf(d[ft][3], 0.f));
      *(uint2*)(hp + ft*16) = u;
    }
  }
}

// out[b,c,n] = h[b,n,:] @ W_out + b_out   (R2/R8-proven)
__global__ void k_out(const __half* __restrict__ h, const float* __restrict__ W_out,
                      const float* __restrict__ b_out, float* __restrict__ out) {
  int idx = blockIdx.x * 256 + threadIdx.x;
  int c8 = idx & 7;
  int bn = idx >> 3;
  uint4 raw = *reinterpret_cast<const uint4*>(h + (size_t)bn*64 + (size_t)c8*8);
  const __half2* hp = reinterpret_cast<const __half2*>(&raw);
  float p0 = 0.f, p1 = 0.f, p2 = 0.f;
  int fbase = c8*8;
#pragma unroll
  for (int j = 0; j < 4; ++j) {
    float2 f = __half22float2(hp[j]);
    const float* wv = &W_out[(fbase + j*2)*3];
    p0 += f.x*wv[0] + f.y*wv[3];
    p1 += f.x*wv[1] + f.y*wv[4];
    p2 += f.x*wv[2] + f.y*wv[5];
  }
#pragma unroll
  for (int m = 1; m < 8; m <<= 1) {
    p0 += __shfl_xor(p0, m);
    p1 += __shfl_xor(p1, m);
    p2 += __shfl_xor(p2, m);
  }
  if (c8 == 0) {
    int b = bn >> 17, n = bn & (NPIX-1);
    out[((size_t)b*3 + 0)*NPIX + n] = p0 + b_out[0];
    out[((size_t)b*3 + 1)*NPIX + n] = p1 + b_out[1];
    out[((size_t)b*3 + 2)*NPIX + n] = p2 + b_out[2];
  }
}

extern "C" void kernel_launch(void* const* d_in, const int* in_sizes, int n_in,
                              void* d_out, int out_size, void* d_ws, size_t ws_size,
                              hipStream_t stream) {
  const float* x     = (const float*)d_in[0];
  // d_in[1] = src, d_in[2] = dst — unused: grid topology is analytic
  const float* W_in  = (const float*)d_in[3];
  const float* b_in  = (const float*)d_in[4];
  const float* Wg    = (const float*)d_in[5];
  const float* bg    = (const float*)d_in[6];
  const float* W_out = (const float*)d_in[7];
  const float* b_out = (const float*)d_in[8];
  float* out = (float*)d_out;

  // WgT fp16 scratch at head of d_out (R2/R8-proven: k_out fully overwrites later)
  __half* WgT = (__half*)d_out;
  __half* hA = (__half*)d_ws;
  __half* hB = hA + (size_t)BATCH*NPIX*HID;

  k_wg<<<dim3(48), 256, 0, stream>>>(Wg, WgT);

  dim3 lg(W_IMG/TX, H_IMG/TY, BATCH);   // 32 x 32 x 4 = 4096 blocks
  k_layer<0><<<lg, LTH, 0, stream>>>(x, W_in, b_in, nullptr, WgT,        bg,       hA);
  k_layer<1><<<lg, LTH, 0, stream>>>(nullptr, nullptr, nullptr, hA, WgT + 4096, bg + 64,  hB);
  k_layer<1><<<lg, LTH, 0, stream>>>(nullptr, nullptr, nullptr, hB, WgT + 8192, bg + 128, hA);

  k_out<<<dim3(BATCH*NPIX*8/256), 256, 0, stream>>>(hA, W_out, b_out, out);
}

// Round 11
// 135.682 us; speedup vs baseline: 2.3371x; 1.1569x over previous
//
#include <hip/hip_runtime.h>
#include <hip/hip_fp16.h>

#define H_IMG 256
#define W_IMG 512
#define NPIX  (H_IMG*W_IMG)   // 131072
#define BATCH 4
#define HID   64

#define TX 32
#define TY 8
#define HX (TX+2)   // 34
#define HY (TY+2)   // 10
#define HN (HX*HY)  // 340
#define LTH 256

// LDS: node-major, 64 halfs (128 B) per node, NO pad (global_load_lds writes
// linearly). Bank conflicts handled by XOR swizzle: chunk c8 of node n lives
// at halfs n*64 + ((c8 ^ (n&7))*8). Staging pre-swizzles the GLOBAL source
// chunk so the linear LDS write lands swizzled (rule: both-sides-or-neither).

typedef _Float16 half8 __attribute__((ext_vector_type(8)));
typedef float v4f __attribute__((ext_vector_type(4)));

#define GLOAD16(gp, lp) \
  __builtin_amdgcn_global_load_lds((const __attribute__((address_space(1))) unsigned int*)(gp), \
                                   (__attribute__((address_space(3))) unsigned int*)(lp), 16, 0, 0)

__device__ __forceinline__ float dinvf(int y, int x) {
  int cy = 3 - (y==0) - (y==(H_IMG-1));
  int cx = 3 - (x==0) - (x==(W_IMG-1));
  return rsqrtf((float)(cy*cx));
}

__device__ __forceinline__ unsigned pack2(float a, float b) {
  __half2 h = __floats2half2_rn(a, b);
  return *reinterpret_cast<unsigned*>(&h);
}

// WgT[l][f][k] = fp16(Wg[l][k][f])   (R2/R8-proven)
__global__ void k_wg(const float* __restrict__ Wg, __half* __restrict__ WgT) {
  int idx = blockIdx.x * 256 + threadIdx.x;          // 3*64*64 = 12288
  int l = idx >> 12, rem = idx & 4095;
  int f = rem >> 6, k = rem & 63;
  WgT[idx] = __float2half(Wg[(l << 12) + (k << 6) + f]);
}

// One GCN layer. MODE 0: build h0 from x on the fly; MODE 1: async-stage from hin.
template<int MODE>
__global__ __launch_bounds__(LTH, 3) void k_layer(
    const float* __restrict__ x,
    const float* __restrict__ W_in, const float* __restrict__ b_in,
    const __half* __restrict__ hin, const __half* __restrict__ wgt,
    const float* __restrict__ bg, __half* __restrict__ hout) {
  __shared__ __half hs[HN * 64];   // 43,520 B -> 3 blocks/CU
  const int tid = threadIdx.x;
  const int tx0 = blockIdx.x * TX;
  const int ty0 = blockIdx.y * TY;
  const int b   = blockIdx.z;

  const int l64 = tid & 63, lm = l64 & 15, lh = l64 >> 4, w = tid >> 6;

  // A fragments (WgT, fp16) + bias C-input (R8-proven)
  half8 af0[4], af1[4];
  v4f cb[4];
#pragma unroll
  for (int ft = 0; ft < 4; ++ft) {
    const __half* wp = wgt + (ft*16 + lm)*64 + lh*8;
    af0[ft] = *(const half8*)wp;
    af1[ft] = *(const half8*)(wp + 32);
    cb[ft] = *(const v4f*)(bg + ft*16 + (lh << 2));
  }

  // ---- staging ----
  if (MODE == 0) {
    // h0 halo built on the fly from x; swizzled ds-writes; OOB -> 0
    const float* xb = x + (size_t)b*3*NPIX;
    for (int n = tid; n < HN; n += LTH) {
      int row = n / HX, col = n - row*HX;
      int gy = ty0 - 1 + row, gx = tx0 - 1 + col;
      __half* hp = &hs[n << 6];
      const int s7 = n & 7;
      if ((unsigned)gy < H_IMG && (unsigned)gx < W_IMG) {
        int gi = (gy << 9) + gx;
        float x0 = xb[gi], x1 = xb[NPIX+gi], x2 = xb[2*NPIX+gi];
#pragma unroll
        for (int c8 = 0; c8 < 8; ++c8) {
          float rr[8];
#pragma unroll
          for (int k = 0; k < 8; ++k) {
            int f = (c8 << 3) + k;
            rr[k] = fmaf(x0, W_in[f], fmaf(x1, W_in[64+f], fmaf(x2, W_in[128+f], b_in[f])));
          }
          uint4 u = make_uint4(pack2(rr[0],rr[1]), pack2(rr[2],rr[3]),
                               pack2(rr[4],rr[5]), pack2(rr[6],rr[7]));
          *(uint4*)(hp + ((c8 ^ s7) << 3)) = u;
        }
      } else {
        uint4 z = make_uint4(0u,0u,0u,0u);
#pragma unroll
        for (int c8 = 0; c8 < 8; ++c8)
          *(uint4*)(hp + ((c8 ^ s7) << 3)) = z;
      }
    }
  } else {
    // async staging: 11 back-to-back global_load_lds (16B) per thread.
    // Global source chunk pre-swizzled; addresses CLAMPED (OOB handled by
    // zeroed stencil scales; clamped data is finite and multiplied by 0).
    const __half* hb = hin + (size_t)b * NPIX * HID;
    for (int it = tid; it < HN*8; it += LTH) {
      int nl = it >> 3;
      int c8s = (it & 7) ^ (nl & 7);
      int row = nl / HX, col = nl - row*HX;
      int sy = ty0 - 1 + row, sx = tx0 - 1 + col;
      sy = max(0, min(H_IMG-1, sy));
      sx = max(0, min(W_IMG-1, sx));
      const __half* gp = hb + ((size_t)((sy << 9) + sx)) * 64 + (c8s << 3);
      GLOAD16(gp, &hs[it << 3]);
    }
  }
  __syncthreads();   // compiler drains vmcnt before barrier

  // ---- 9-point stencil, fp32 acc; swizzled LDS reads; OOB via zero scales ----
  const int lx = tid & 31, ly = tid >> 5;
  const int gy = ty0 + ly, gx = tx0 + lx;
  const float dc = dinvf(gy, gx);
  float sc[9];
  int   nbn[9];
#pragma unroll
  for (int r = 0; r < 3; ++r)
#pragma unroll
    for (int c = 0; c < 3; ++c) {
      int ny = gy - 1 + r, nx = gx - 1 + c;
      bool ok = ((unsigned)ny < H_IMG) && ((unsigned)nx < W_IMG);
      sc[r*3+c] = ok ? dc * dinvf(ny, nx) : 0.f;
      nbn[r*3+c] = (ly + r)*HX + lx + c;   // node index in halo
    }
  half8 sreg[8];
#pragma unroll
  for (int ch = 0; ch < 8; ++ch) {
    float acc[8] = {0.f,0.f,0.f,0.f,0.f,0.f,0.f,0.f};
#pragma unroll
    for (int j = 0; j < 9; ++j) {
      int nj = nbn[j];
      half8 v = *(const half8*)&hs[(nj << 6) + (((ch ^ (nj & 7))) << 3)];
      float s = sc[j];
#pragma unroll
      for (int k = 0; k < 8; ++k) acc[k] = fmaf(s, (float)v[k], acc[k]);
    }
    half8 o;
#pragma unroll
    for (int k = 0; k < 8; ++k) o[k] = (_Float16)acc[k];
    sreg[ch] = o;
  }
  __syncthreads();                 // all halo reads done; safe to overwrite

  // spill s (fp16) into LDS, node = tid, swizzled chunks
  {
    __half* hp = &hs[tid << 6];
    const int s7 = tid & 7;
#pragma unroll
    for (int ch = 0; ch < 8; ++ch)
      *(half8*)(hp + ((ch ^ s7) << 3)) = sreg[ch];
  }
  __syncthreads();

  // ---- GEMM: D = WgT (64f x 64k) x s^T; D[f][node]; swizzled b-frag reads ----
  __half* ho = hout + (size_t)b * NPIX * HID;
#pragma unroll
  for (int i = 0; i < 4; ++i) {
    int g  = (w << 2) + i;          // node group: 16 nodes
    int nn = (g << 4) + lm;         // local node for this lane (= tid ordering)
    const int s7 = nn & 7;
    const __half* np = &hs[nn << 6];
    half8 b0 = *(const half8*)(np + ((lh ^ s7) << 3));
    half8 b1 = *(const half8*)(np + (((lh + 4) ^ s7) << 3));
    v4f d[4];
#pragma unroll
    for (int ft = 0; ft < 4; ++ft) {
      v4f t = __builtin_amdgcn_mfma_f32_16x16x32_f16(af0[ft], b0, cb[ft], 0, 0, 0);
      d[ft]  = __builtin_amdgcn_mfma_f32_16x16x32_f16(af1[ft], b1, t,     0, 0, 0);
    }
    // lane holds features ft*16 + lh*4 + r of node nn; node nn: row nn>>5, col nn&31
    __half* hp = ho + (size_t)(((ty0 + (nn >> 5)) << 9) + tx0 + (nn & 31)) * HID + (lh << 2);
#pragma unroll
    for (int ft = 0; ft < 4; ++ft) {
      uint2 u;
      u.x = pack2(fmaxf(d[ft][0], 0.f), fmaxf(d[ft][1], 0.f));
      u.y = pack2(fmaxf(d[ft][2], 0.f), fmaxf(d[ft][3], 0.f));
      *(uint2*)(hp + ft*16) = u;
    }
  }
}

// out[b,c,n] = h[b,n,:] @ W_out + b_out   (R2/R8-proven)
__global__ void k_out(const __half* __restrict__ h, const float* __restrict__ W_out,
                      const float* __restrict__ b_out, float* __restrict__ out) {
  int idx = blockIdx.x * 256 + threadIdx.x;
  int c8 = idx & 7;
  int bn = idx >> 3;
  uint4 raw = *reinterpret_cast<const uint4*>(h + (size_t)bn*64 + (size_t)c8*8);
  const __half2* hp = reinterpret_cast<const __half2*>(&raw);
  float p0 = 0.f, p1 = 0.f, p2 = 0.f;
  int fbase = c8*8;
#pragma unroll
  for (int j = 0; j < 4; ++j) {
    float2 f = __half22float2(hp[j]);
    const float* wv = &W_out[(fbase + j*2)*3];
    p0 += f.x*wv[0] + f.y*wv[3];
    p1 += f.x*wv[1] + f.y*wv[4];
    p2 += f.x*wv[2] + f.y*wv[5];
  }
#pragma unroll
  for (int m = 1; m < 8; m <<= 1) {
    p0 += __shfl_xor(p0, m);
    p1 += __shfl_xor(p1, m);
    p2 += __shfl_xor(p2, m);
  }
  if (c8 == 0) {
    int b = bn >> 17, n = bn & (NPIX-1);
    out[((size_t)b*3 + 0)*NPIX + n] = p0 + b_out[0];
    out[((size_t)b*3 + 1)*NPIX + n] = p1 + b_out[1];
    out[((size_t)b*3 + 2)*NPIX + n] = p2 + b_out[2];
  }
}

extern "C" void kernel_launch(void* const* d_in, const int* in_sizes, int n_in,
                              void* d_out, int out_size, void* d_ws, size_t ws_size,
                              hipStream_t stream) {
  const float* x     = (const float*)d_in[0];
  // d_in[1] = src, d_in[2] = dst — unused: grid topology is analytic
  const float* W_in  = (const float*)d_in[3];
  const float* b_in  = (const float*)d_in[4];
  const float* Wg    = (const float*)d_in[5];
  const float* bg    = (const float*)d_in[6];
  const float* W_out = (const float*)d_in[7];
  const float* b_out = (const float*)d_in[8];
  float* out = (float*)d_out;

  // WgT fp16 scratch at head of d_out (R2/R8-proven: k_out fully overwrites later)
  __half* WgT = (__half*)d_out;
  __half* hA = (__half*)d_ws;
  __half* hB = hA + (size_t)BATCH*NPIX*HID;

  k_wg<<<dim3(48), 256, 0, stream>>>(Wg, WgT);

  dim3 lg(W_IMG/TX, H_IMG/TY, BATCH);   // 16 x 32 x 4
  k_layer<0><<<lg, LTH, 0, stream>>>(x, W_in, b_in, nullptr, WgT,        bg,       hA);
  k_layer<1><<<lg, LTH, 0, stream>>>(nullptr, nullptr, nullptr, hA, WgT + 4096, bg + 64,  hB);
  k_layer<1><<<lg, LTH, 0, stream>>>(nullptr, nullptr, nullptr, hB, WgT + 8192, bg + 128, hA);

  k_out<<<dim3(BATCH*NPIX*8/256), 256, 0, stream>>>(hA, W_out, b_out, out);
}